// Round 1
// baseline (658.489 us; speedup 1.0000x reference)
//
#include <hip/hip_runtime.h>
#include <hip/hip_cooperative_groups.h>
#include <math.h>

namespace cg = cooperative_groups;

// Problem constants
#define B_   16
#define C_   512
#define HW_  4096
#define T_   768
#define NH   12
#define DH   64

typedef float nfloat4 __attribute__((ext_vector_type(4)));

// Workspace layout (floats), parametrized by CS (c-split count):
//   qkT  @ 0            [B][C][NH]        98304
//   qb   @ 98304        [B*NH]            192
//   sp   @ 98496        [CS][B][NH][HW]   CS*786432
//   attn @ 98496+CS*786432   [B][NH][HW]  786432
//   y    @ attn+786432  [B][NH][C]        98304
//   outT @ y+98304      [B][T]            12288
//   z    @ outT+12288   [B][C]            8192

// ===========================================================================
// Cooperative mega-kernel: all 7 stages, separated by grid.sync().
// grid-stride in every phase so any co-resident grid size works.
// ===========================================================================
template <int CS>
__global__ __launch_bounds__(256, 4) void mega_kernel(
    const float* __restrict__ cond, const float* __restrict__ tvec,
    const float* __restrict__ Wk, const float* __restrict__ bk,
    const float* __restrict__ Wv, const float* __restrict__ bv,
    const float* __restrict__ Wo, const float* __restrict__ bo,
    float* __restrict__ out, float* __restrict__ ws) {
  constexpr int CB = C_ / CS;  // 64 for CS=8, 128 for CS=4
  float* qkT  = ws;
  float* qb   = ws + 98304;
  float* sp   = ws + 98496;
  float* attn = sp + (size_t)CS * 786432;
  float* y    = attn + 786432;
  float* outT = y + 98304;
  float* z    = outT + 12288;
  const float* x = cond;

  cg::grid_group grid = cg::this_grid();
  const int tid = threadIdx.x;
  const int nb  = gridDim.x;

  __shared__ float lds[1536];  // reused by every phase (max: qc for CS=4)

  // ---- Phase 0: qkT[b][c][h] = (1/8) sum_dd t[b,h*64+dd]*Wk[h*64+dd,c]; qb.
  for (int u = blockIdx.x; u < B_ * NH; u += nb) {
    int b = u / NH, h = u % NH;
    if (tid < DH) lds[tid] = tvec[b * T_ + h * DH + tid];
    __syncthreads();
#pragma unroll
    for (int cc = 0; cc < 2; ++cc) {
      int c = cc * 256 + tid;
      float acc = 0.f;
#pragma unroll
      for (int dd = 0; dd < DH; ++dd)
        acc += lds[dd] * Wk[(h * DH + dd) * C_ + c];
      qkT[((size_t)b * C_ + c) * NH + h] = acc * 0.125f;
    }
    if (tid == 0) {
      float s = 0.f;
      for (int dd = 0; dd < DH; ++dd) s += lds[dd] * bk[h * DH + dd];
      qb[u] = s * 0.125f;
    }
    __syncthreads();
  }
  grid.sync();

  // ---- Phase 1: partial scores. sp[cs][b][h][m] = sum_{c in slice} qk*x.
  // 256 threads/block, float2 of m per thread -> 4 waves/SIMD at full grid.
  for (int u = blockIdx.x; u < 8 * CS * B_; u += nb) {
    int mt = u & 7;
    int cs = (u >> 3) % CS;
    int b  = u / (8 * CS);
    const float* src = qkT + ((size_t)b * C_ + cs * CB) * NH;
    for (int i = tid; i < CB * NH; i += 256) lds[i] = src[i];
    __syncthreads();
    int m0 = mt * 512 + tid * 2;
    float ax[NH], ay[NH];
#pragma unroll
    for (int h = 0; h < NH; ++h) { ax[h] = 0.f; ay[h] = 0.f; }
    const float* xb = x + (size_t)b * C_ * HW_ + (size_t)(cs * CB) * HW_ + m0;
    for (int c0 = 0; c0 < CB; c0 += 16) {
      float2 xv[16];
#pragma unroll
      for (int j = 0; j < 16; ++j)
        xv[j] = *(const float2*)(xb + (size_t)(c0 + j) * HW_);
#pragma unroll
      for (int j = 0; j < 16; ++j) {
        // q-vector for this c: 12 floats, 48B-aligned -> 3x ds_read_b128
        const float4* q4 = (const float4*)(lds + (c0 + j) * NH);
        float4 qa = q4[0], qb2 = q4[1], qc2 = q4[2];
        ax[0] += qa.x * xv[j].x;  ay[0] += qa.x * xv[j].y;
        ax[1] += qa.y * xv[j].x;  ay[1] += qa.y * xv[j].y;
        ax[2] += qa.z * xv[j].x;  ay[2] += qa.z * xv[j].y;
        ax[3] += qa.w * xv[j].x;  ay[3] += qa.w * xv[j].y;
        ax[4] += qb2.x * xv[j].x; ay[4] += qb2.x * xv[j].y;
        ax[5] += qb2.y * xv[j].x; ay[5] += qb2.y * xv[j].y;
        ax[6] += qb2.z * xv[j].x; ay[6] += qb2.z * xv[j].y;
        ax[7] += qb2.w * xv[j].x; ay[7] += qb2.w * xv[j].y;
        ax[8] += qc2.x * xv[j].x; ay[8] += qc2.x * xv[j].y;
        ax[9] += qc2.y * xv[j].x; ay[9] += qc2.y * xv[j].y;
        ax[10] += qc2.z * xv[j].x; ay[10] += qc2.z * xv[j].y;
        ax[11] += qc2.w * xv[j].x; ay[11] += qc2.w * xv[j].y;
      }
    }
    float* spp = sp + ((size_t)cs * B_ * NH + (size_t)b * NH) * HW_ + m0;
#pragma unroll
    for (int h = 0; h < NH; ++h) {
      float2 v; v.x = ax[h]; v.y = ay[h];
      *(float2*)(spp + (size_t)h * HW_) = v;
    }
    __syncthreads();
  }
  grid.sync();

  // ---- Phase 2: combine partials + qb, softmax over m=4096. 192 rows.
  for (int u = blockIdx.x; u < B_ * NH; u += nb) {
    float qbv = qb[u];
    const size_t S4 = (size_t)B_ * NH * (HW_ / 4);
    const float4* p = (const float4*)sp + (size_t)u * (HW_ / 4);
    float4 v[4];
#pragma unroll
    for (int k = 0; k < 4; ++k) {
      int idx = k * 256 + tid;
      float4 vv = make_float4(qbv, qbv, qbv, qbv);
#pragma unroll
      for (int s = 0; s < CS; ++s) {
        float4 pv = p[(size_t)s * S4 + idx];
        vv.x += pv.x; vv.y += pv.y; vv.z += pv.z; vv.w += pv.w;
      }
      v[k] = vv;
    }
    float vmax = -1e30f;
#pragma unroll
    for (int k = 0; k < 4; ++k)
      vmax = fmaxf(vmax, fmaxf(fmaxf(v[k].x, v[k].y), fmaxf(v[k].z, v[k].w)));
    for (int off = 32; off; off >>= 1) vmax = fmaxf(vmax, __shfl_xor(vmax, off));
    if ((tid & 63) == 0) lds[tid >> 6] = vmax;
    __syncthreads();
    vmax = fmaxf(fmaxf(lds[0], lds[1]), fmaxf(lds[2], lds[3]));
    float sum = 0.f;
#pragma unroll
    for (int k = 0; k < 4; ++k) {
      v[k].x = __expf(v[k].x - vmax); v[k].y = __expf(v[k].y - vmax);
      v[k].z = __expf(v[k].z - vmax); v[k].w = __expf(v[k].w - vmax);
      sum += v[k].x + v[k].y + v[k].z + v[k].w;
    }
    for (int off = 32; off; off >>= 1) sum += __shfl_xor(sum, off);
    if ((tid & 63) == 0) lds[4 + (tid >> 6)] = sum;
    __syncthreads();
    float inv = 1.f / (lds[4] + lds[5] + lds[6] + lds[7]);
    float4* ap = (float4*)attn + (size_t)u * (HW_ / 4);
#pragma unroll
    for (int k = 0; k < 4; ++k) {
      int idx = k * 256 + tid;
      float4 vv = v[k];
      vv.x *= inv; vv.y *= inv; vv.z *= inv; vv.w *= inv;
      ap[idx] = vv;
    }
    __syncthreads();
  }
  grid.sync();

  // ---- Phase 3: y[b][h][c] = sum_m attn[b,h,m] * x[b,c,m]. 2048 units.
  for (int u = blockIdx.x; u < 128 * B_; u += nb) {
    int cgrp = u & 127;
    int b = u >> 7;
    int c0 = cgrp * 4;
    float acc[4][NH];
#pragma unroll
    for (int g = 0; g < 4; ++g)
#pragma unroll
      for (int h = 0; h < NH; ++h) acc[g][h] = 0.f;
    const float4* xb = (const float4*)(x + (size_t)b * C_ * HW_ + (size_t)c0 * HW_);
    const float4* ab = (const float4*)(attn + (size_t)b * NH * HW_);
#pragma unroll 1
    for (int k = 0; k < 4; ++k) {
      int m4 = k * 256 + tid;
      float4 xv[4];
#pragma unroll
      for (int g = 0; g < 4; ++g) xv[g] = xb[(size_t)g * (HW_ / 4) + m4];
#pragma unroll
      for (int hh = 0; hh < NH; hh += 4) {
        float4 a[4];
#pragma unroll
        for (int h = 0; h < 4; ++h) a[h] = ab[(size_t)(hh + h) * (HW_ / 4) + m4];
#pragma unroll
        for (int g = 0; g < 4; ++g)
#pragma unroll
          for (int h = 0; h < 4; ++h)
            acc[g][hh + h] += a[h].x * xv[g].x + a[h].y * xv[g].y +
                              a[h].z * xv[g].z + a[h].w * xv[g].w;
      }
    }
#pragma unroll
    for (int g = 0; g < 4; ++g)
#pragma unroll
      for (int h = 0; h < NH; ++h)
        for (int off = 32; off; off >>= 1)
          acc[g][h] += __shfl_xor(acc[g][h], off);
    int w = tid >> 6, lane = tid & 63;
    if (lane == 0) {
#pragma unroll
      for (int g = 0; g < 4; ++g)
#pragma unroll
        for (int h = 0; h < NH; ++h) lds[w * 48 + g * NH + h] = acc[g][h];
    }
    __syncthreads();
    if (tid < 48) {
      float s = lds[tid] + lds[48 + tid] + lds[96 + tid] + lds[144 + tid];
      int g = tid / NH, h = tid % NH;
      y[((size_t)b * NH + h) * C_ + c0 + g] = s;
    }
    __syncthreads();
  }
  grid.sync();

  // ---- Phase 4: outT[b][t] = bv[t] + sum_c Wv[t,c] * y[b][t/64][c]
  for (int u = blockIdx.x; u < (B_ * T_) / 4; u += nb) {
    int o = u * 4 + (tid >> 6);
    int lane = tid & 63;
    int b = o / T_, to = o % T_;
    int h = to / DH;
    const float* wr = Wv + (size_t)to * C_;
    const float* yr = y + ((size_t)b * NH + h) * C_;
    float s = 0.f;
#pragma unroll
    for (int j = 0; j < 8; ++j) { int c = j * 64 + lane; s += wr[c] * yr[c]; }
    for (int off = 32; off; off >>= 1) s += __shfl_xor(s, off);
    if (lane == 0) outT[o] = s + bv[to];
  }
  grid.sync();

  // ---- Phase 5: z[b][c] = bo[c] + sum_t Wo[c,t] * outT[b][t]
  for (int u = blockIdx.x; u < (B_ * C_) / 4; u += nb) {
    int o = u * 4 + (tid >> 6);
    int lane = tid & 63;
    int b = o / C_, c = o % C_;
    const float* wr = Wo + (size_t)c * T_;
    const float* orr = outT + (size_t)b * T_;
    float s = 0.f;
#pragma unroll
    for (int j = 0; j < 12; ++j) { int t2 = j * 64 + lane; s += wr[t2] * orr[t2]; }
    for (int off = 32; off; off >>= 1) s += __shfl_xor(s, off);
    if (lane == 0) z[o] = s + bo[c];
  }
  grid.sync();

  // ---- Phase 6: out = cond + z (broadcast), nontemporal streaming.
  {
    const size_t total4 = (size_t)B_ * C_ * HW_ / 4;  // 8388608
    const size_t stride = (size_t)nb * 256;
    size_t i = (size_t)blockIdx.x * 256 + tid;
    for (; i + 3 * stride < total4; i += 4 * stride) {
      size_t i1 = i + stride, i2 = i + 2 * stride, i3 = i + 3 * stride;
      nfloat4 c0v = __builtin_nontemporal_load(&((const nfloat4*)cond)[i]);
      nfloat4 c1v = __builtin_nontemporal_load(&((const nfloat4*)cond)[i1]);
      nfloat4 c2v = __builtin_nontemporal_load(&((const nfloat4*)cond)[i2]);
      nfloat4 c3v = __builtin_nontemporal_load(&((const nfloat4*)cond)[i3]);
      float z0 = z[i >> 10], z1 = z[i1 >> 10], z2 = z[i2 >> 10], z3 = z[i3 >> 10];
      __builtin_nontemporal_store(c0v + z0, &((nfloat4*)out)[i]);
      __builtin_nontemporal_store(c1v + z1, &((nfloat4*)out)[i1]);
      __builtin_nontemporal_store(c2v + z2, &((nfloat4*)out)[i2]);
      __builtin_nontemporal_store(c3v + z3, &((nfloat4*)out)[i3]);
    }
    for (; i < total4; i += stride) {
      nfloat4 cv = __builtin_nontemporal_load(&((const nfloat4*)cond)[i]);
      __builtin_nontemporal_store(cv + z[i >> 10], &((nfloat4*)out)[i]);
    }
  }
}

// ===========================================================================
// Fallback: the previous 7-kernel pipeline, verbatim (used only if
// cooperative launch is unavailable).
// ===========================================================================
__global__ __launch_bounds__(512) void qk_kernel(
    const float* __restrict__ t, const float* __restrict__ Wk,
    const float* __restrict__ bk, float* __restrict__ qkT,
    float* __restrict__ qb) {
  int bh = blockIdx.x;
  int b = bh / NH, h = bh % NH;
  __shared__ float tl[DH];
  int tid = threadIdx.x;
  if (tid < DH) tl[tid] = t[b * T_ + h * DH + tid];
  __syncthreads();
  int c = tid;
  float acc = 0.f;
#pragma unroll
  for (int dd = 0; dd < DH; ++dd)
    acc += tl[dd] * Wk[(h * DH + dd) * C_ + c];
  qkT[((size_t)b * C_ + c) * NH + h] = acc * 0.125f;
  if (tid == 0) {
    float s = 0.f;
    for (int dd = 0; dd < DH; ++dd) s += tl[dd] * bk[h * DH + dd];
    qb[bh] = s * 0.125f;
  }
}

template <int CS>
__global__ __launch_bounds__(128) void s_kernel(
    const float* __restrict__ x, const float* __restrict__ qkT,
    float* __restrict__ sp) {
  constexpr int CB = C_ / CS;
  int mt = blockIdx.x;
  int cs = blockIdx.y;
  int b  = blockIdx.z;
  int tid = threadIdx.x;

  __shared__ float qc[CB * NH];
  const float* src = qkT + ((size_t)b * C_ + cs * CB) * NH;
  for (int i = tid; i < CB * NH; i += 128) qc[i] = src[i];
  __syncthreads();

  int m0 = mt * 512 + tid * 4;
  float4 acc[NH];
#pragma unroll
  for (int h = 0; h < NH; ++h) acc[h] = make_float4(0.f, 0.f, 0.f, 0.f);

  const float* xb = x + (size_t)b * C_ * HW_ + (size_t)(cs * CB) * HW_ + m0;
  for (int c0 = 0; c0 < CB; c0 += 16) {
    float4 xv[16];
#pragma unroll
    for (int j = 0; j < 16; ++j)
      xv[j] = *(const float4*)(xb + (size_t)(c0 + j) * HW_);
#pragma unroll
    for (int j = 0; j < 16; ++j) {
      const float* q = qc + (c0 + j) * NH;
#pragma unroll
      for (int h = 0; h < NH; ++h) {
        float qh = q[h];
        acc[h].x += qh * xv[j].x; acc[h].y += qh * xv[j].y;
        acc[h].z += qh * xv[j].z; acc[h].w += qh * xv[j].w;
      }
    }
  }
  float* spp = sp + ((size_t)cs * B_ * NH + (size_t)b * NH) * HW_ + m0;
#pragma unroll
  for (int h = 0; h < NH; ++h)
    *(float4*)(spp + (size_t)h * HW_) = acc[h];
}

template <int CS>
__global__ __launch_bounds__(1024) void softmax_kernel(
    const float* __restrict__ sp, const float* __restrict__ qb,
    float* __restrict__ attn) {
  int bh = blockIdx.x;
  int tid = threadIdx.x;
  float qbv = qb[bh];
  const size_t S4 = (size_t)B_ * NH * (HW_ / 4);
  const float4* p = (const float4*)sp + (size_t)bh * (HW_ / 4) + tid;

  float4 v = make_float4(qbv, qbv, qbv, qbv);
#pragma unroll
  for (int s = 0; s < CS; ++s) {
    float4 pv = p[s * S4];
    v.x += pv.x; v.y += pv.y; v.z += pv.z; v.w += pv.w;
  }

  float vmax = fmaxf(fmaxf(v.x, v.y), fmaxf(v.z, v.w));
  for (int off = 32; off; off >>= 1) vmax = fmaxf(vmax, __shfl_xor(vmax, off));
  __shared__ float redm[16], reds[16];
  int w = tid >> 6;
  if ((tid & 63) == 0) redm[w] = vmax;
  __syncthreads();
  vmax = redm[0];
#pragma unroll
  for (int i = 1; i < 16; ++i) vmax = fmaxf(vmax, redm[i]);

  v.x = __expf(v.x - vmax); v.y = __expf(v.y - vmax);
  v.z = __expf(v.z - vmax); v.w = __expf(v.w - vmax);
  float sum = v.x + v.y + v.z + v.w;
  for (int off = 32; off; off >>= 1) sum += __shfl_xor(sum, off);
  if ((tid & 63) == 0) reds[w] = sum;
  __syncthreads();
  float tot = reds[0];
#pragma unroll
  for (int i = 1; i < 16; ++i) tot += reds[i];
  float inv = 1.f / tot;
  v.x *= inv; v.y *= inv; v.z *= inv; v.w *= inv;
  ((float4*)attn)[(size_t)bh * (HW_ / 4) + tid] = v;
}

__global__ __launch_bounds__(256) void y_kernel(
    const float* __restrict__ x, const float* __restrict__ attn,
    float* __restrict__ y) {
  int cg = blockIdx.x;
  int b  = blockIdx.y;
  int tid = threadIdx.x;
  int c0 = cg * 4;

  float acc[4][NH] = {};
  const float4* xb = (const float4*)(x + (size_t)b * C_ * HW_ + (size_t)c0 * HW_);
  const float4* ab = (const float4*)(attn + (size_t)b * NH * HW_);
#pragma unroll 1
  for (int k = 0; k < 4; ++k) {
    int m4 = k * 256 + tid;
    float4 xv[4];
#pragma unroll
    for (int g = 0; g < 4; ++g) xv[g] = xb[(size_t)g * (HW_ / 4) + m4];
    float4 a[NH];
#pragma unroll
    for (int h = 0; h < NH; ++h) a[h] = ab[(size_t)h * (HW_ / 4) + m4];
#pragma unroll
    for (int g = 0; g < 4; ++g)
#pragma unroll
      for (int h = 0; h < NH; ++h)
        acc[g][h] += a[h].x * xv[g].x + a[h].y * xv[g].y +
                     a[h].z * xv[g].z + a[h].w * xv[g].w;
  }
#pragma unroll
  for (int g = 0; g < 4; ++g)
#pragma unroll
    for (int h = 0; h < NH; ++h)
      for (int off = 32; off; off >>= 1)
        acc[g][h] += __shfl_xor(acc[g][h], off);

  __shared__ float red[4][48];
  int w = tid >> 6, lane = tid & 63;
  if (lane == 0) {
#pragma unroll
    for (int g = 0; g < 4; ++g)
#pragma unroll
      for (int h = 0; h < NH; ++h) red[w][g * NH + h] = acc[g][h];
  }
  __syncthreads();
  if (tid < 48) {
    float s = red[0][tid] + red[1][tid] + red[2][tid] + red[3][tid];
    int g = tid / NH, h = tid % NH;
    y[((size_t)b * NH + h) * C_ + c0 + g] = s;
  }
}

__global__ __launch_bounds__(256) void out_kernel(
    const float* __restrict__ Wv, const float* __restrict__ bv,
    const float* __restrict__ y, float* __restrict__ outT) {
  int o = blockIdx.x * 4 + (threadIdx.x >> 6);
  int lane = threadIdx.x & 63;
  int b = o / T_, t = o % T_;
  int h = t / DH;
  const float* wr = Wv + (size_t)t * C_;
  const float* yr = y + ((size_t)b * NH + h) * C_;
  float s = 0.f;
#pragma unroll
  for (int j = 0; j < 8; ++j) { int c = j * 64 + lane; s += wr[c] * yr[c]; }
  for (int off = 32; off; off >>= 1) s += __shfl_xor(s, off);
  if (lane == 0) outT[o] = s + bv[t];
}

__global__ __launch_bounds__(256) void z_kernel(
    const float* __restrict__ Wo, const float* __restrict__ bo,
    const float* __restrict__ outT, float* __restrict__ z) {
  int o = blockIdx.x * 4 + (threadIdx.x >> 6);
  int lane = threadIdx.x & 63;
  int b = o / C_, c = o % C_;
  const float* wr = Wo + (size_t)c * T_;
  const float* orr = outT + (size_t)b * T_;
  float s = 0.f;
#pragma unroll
  for (int j = 0; j < 12; ++j) { int t = j * 64 + lane; s += wr[t] * orr[t]; }
  for (int off = 32; off; off >>= 1) s += __shfl_xor(s, off);
  if (lane == 0) z[o] = s + bo[c];
}

__global__ __launch_bounds__(256) void add_kernel(
    const float* __restrict__ cond, const float* __restrict__ z,
    float* __restrict__ out) {
  size_t i0 = (size_t)blockIdx.x * 512 + threadIdx.x;
  size_t i1 = i0 + 256;
  nfloat4 c0 = __builtin_nontemporal_load(&((const nfloat4*)cond)[i0]);
  nfloat4 c1 = __builtin_nontemporal_load(&((const nfloat4*)cond)[i1]);
  float z0 = z[(int)(i0 >> 10)];
  float z1 = z[(int)(i1 >> 10)];
  nfloat4 r0 = c0 + z0;
  nfloat4 r1 = c1 + z1;
  __builtin_nontemporal_store(r0, &((nfloat4*)out)[i0]);
  __builtin_nontemporal_store(r1, &((nfloat4*)out)[i1]);
}

template <int CS>
static void run_pipeline(const float* cond, const float* t, const float* Wk,
                         const float* bk, const float* Wv, const float* bv,
                         const float* Wo, const float* bo, float* out,
                         float* ws, int out_size, hipStream_t stream) {
  float* qkT  = ws;
  float* qb   = ws + 98304;
  float* sp   = ws + 98496;
  float* attn = sp + (size_t)CS * 786432;
  float* y    = attn + 786432;
  float* outT = y + 98304;
  float* z    = outT + 12288;

  hipLaunchKernelGGL(qk_kernel, dim3(B_ * NH), dim3(512), 0, stream,
                     t, Wk, bk, qkT, qb);
  hipLaunchKernelGGL((s_kernel<CS>), dim3(8, CS, B_), dim3(128), 0, stream,
                     cond, qkT, sp);
  hipLaunchKernelGGL((softmax_kernel<CS>), dim3(B_ * NH), dim3(1024), 0, stream,
                     sp, qb, attn);
  hipLaunchKernelGGL(y_kernel, dim3(128, B_), dim3(256), 0, stream,
                     cond, attn, y);
  hipLaunchKernelGGL(out_kernel, dim3((B_ * T_) / 4), dim3(256), 0, stream,
                     Wv, bv, y, outT);
  hipLaunchKernelGGL(z_kernel, dim3((B_ * C_) / 4), dim3(256), 0, stream,
                     Wo, bo, outT, z);
  hipLaunchKernelGGL(add_kernel, dim3(out_size / 4 / 512), dim3(256), 0,
                     stream, cond, z, out);
}

// ===========================================================================
extern "C" void kernel_launch(void* const* d_in, const int* in_sizes, int n_in,
                              void* d_out, int out_size, void* d_ws, size_t ws_size,
                              hipStream_t stream) {
  const float* cond = (const float*)d_in[0];
  const float* t    = (const float*)d_in[1];
  const float* Wk   = (const float*)d_in[2];
  const float* bk   = (const float*)d_in[3];
  const float* Wv   = (const float*)d_in[4];
  const float* bv   = (const float*)d_in[5];
  const float* Wo   = (const float*)d_in[6];
  const float* bo   = (const float*)d_in[7];
  float* out = (float*)d_out;
  float* ws  = (float*)d_ws;

  const size_t need8 = (size_t)(98496 + 8 * 786432 + 786432 + 98304 + 12288 + 8192) * 4;
  const bool use8 = ws_size >= need8;

  // One-time host-side queries (no stream ops; graph-capture safe).
  static int nb8 = -2, nb4 = -2;
  if (nb8 == -2) {
    int dev = 0, coop = 0, ncu = 256;
    hipGetDevice(&dev);
    hipDeviceGetAttribute(&coop, hipDeviceAttributeCooperativeLaunch, dev);
    hipDeviceGetAttribute(&ncu, hipDeviceAttributeMultiprocessorCount, dev);
    if (ncu <= 0) ncu = 256;
    if (coop) {
      int m8 = 0, m4 = 0;
      hipError_t e1 = hipOccupancyMaxActiveBlocksPerMultiprocessor(&m8, mega_kernel<8>, 256, 0);
      hipError_t e2 = hipOccupancyMaxActiveBlocksPerMultiprocessor(&m4, mega_kernel<4>, 256, 0);
      nb8 = (e1 == hipSuccess && m8 >= 1)
                ? ((m8 * ncu > 2048) ? 2048 : m8 * ncu) : -1;
      nb4 = (e2 == hipSuccess && m4 >= 1)
                ? ((m4 * ncu > 2048) ? 2048 : m4 * ncu) : -1;
    } else {
      nb8 = -1; nb4 = -1;
    }
  }

  int nb = use8 ? nb8 : nb4;
  if (nb > 0) {
    void* args[] = {(void*)&cond, (void*)&t, (void*)&Wk, (void*)&bk,
                    (void*)&Wv, (void*)&bv, (void*)&Wo, (void*)&bo,
                    (void*)&out, (void*)&ws};
    if (use8)
      hipLaunchCooperativeKernel(mega_kernel<8>, dim3(nb), dim3(256), args, 0, stream);
    else
      hipLaunchCooperativeKernel(mega_kernel<4>, dim3(nb), dim3(256), args, 0, stream);
  } else {
    if (use8)
      run_pipeline<8>(cond, t, Wk, bk, Wv, bv, Wo, bo, out, ws, out_size, stream);
    else
      run_pipeline<4>(cond, t, Wk, bk, Wv, bv, Wo, bo, out, ws, out_size, stream);
  }
}

// Round 2
// 332.449 us; speedup vs baseline: 1.9807x; 1.9807x over previous
//
#include <hip/hip_runtime.h>
#include <math.h>

// Problem constants
#define B_   16
#define C_   512
#define HW_  4096
#define T_   768
#define NH   12
#define DH   64

typedef float nfloat4 __attribute__((ext_vector_type(4)));

// Workspace layout (floats), parametrized by CS (c-split count):
//   qkT  @ 0            [B][C][NH]        98304
//   qb   @ 98304        [B*NH]            192
//   sp   @ 98496        [CS][B][NH][HW]   CS*786432
//   attn @ 98496+CS*786432   [B][NH][HW]  786432
//   y    @ attn+786432  [B][NH][C]        98304
//   outT @ y+98304      [B][T]            12288
//   z    @ outT+12288   [B][C]            8192

// ---------------------------------------------------------------------------
// Kernel A: qkT[b][c][h] = (1/8) * sum_dd t[b, h*64+dd] * Wk[h*64+dd, c]
//           qb[b*12+h]   = (1/8) * sum_dd t[b, h*64+dd] * bk[h*64+dd]
__global__ __launch_bounds__(512) void qk_kernel(
    const float* __restrict__ t, const float* __restrict__ Wk,
    const float* __restrict__ bk, float* __restrict__ qkT,
    float* __restrict__ qb) {
  int bh = blockIdx.x;
  int b = bh / NH, h = bh % NH;
  __shared__ float tl[DH];
  int tid = threadIdx.x;
  if (tid < DH) tl[tid] = t[b * T_ + h * DH + tid];
  __syncthreads();
  int c = tid;
  float acc = 0.f;
#pragma unroll
  for (int dd = 0; dd < DH; ++dd)
    acc += tl[dd] * Wk[(h * DH + dd) * C_ + c];
  qkT[((size_t)b * C_ + c) * NH + h] = acc * 0.125f;
  if (tid == 0) {
    float s = 0.f;
    for (int dd = 0; dd < DH; ++dd) s += tl[dd] * bk[h * DH + dd];
    qb[bh] = s * 0.125f;
  }
}

// ---------------------------------------------------------------------------
// Kernel B: partial scores. sp[cs][b][h][m] = sum_{c in cs-range} qk[b,h,c]*x[b,c,m]
// grid (mt=8, cs=CS, b=16), block 256; each thread owns one float2 of m.
// 16 x-loads hoisted per group (128 B/lane in flight); 4 waves/SIMD at CS=16.
template <int CS>
__global__ __launch_bounds__(256) void s_kernel(
    const float* __restrict__ x, const float* __restrict__ qkT,
    float* __restrict__ sp) {
  constexpr int CB = C_ / CS;  // 32 for CS=16
  int mt = blockIdx.x;
  int cs = blockIdx.y;
  int b  = blockIdx.z;
  int tid = threadIdx.x;

  __shared__ float qc[CB * NH];
  const float* src = qkT + ((size_t)b * C_ + cs * CB) * NH;
  for (int i = tid; i < CB * NH; i += 256) qc[i] = src[i];
  __syncthreads();

  int m0 = mt * 512 + tid * 2;
  float ax[NH], ay[NH];
#pragma unroll
  for (int h = 0; h < NH; ++h) { ax[h] = 0.f; ay[h] = 0.f; }

  const float* xb = x + (size_t)b * C_ * HW_ + (size_t)(cs * CB) * HW_ + m0;
  for (int c0 = 0; c0 < CB; c0 += 16) {
    float2 xv[16];
#pragma unroll
    for (int j = 0; j < 16; ++j)
      xv[j] = *(const float2*)(xb + (size_t)(c0 + j) * HW_);
#pragma unroll
    for (int j = 0; j < 16; ++j) {
      // q-vector for this c: 12 floats, 16B-aligned -> 3x ds_read_b128
      const float4* q4 = (const float4*)(qc + (c0 + j) * NH);
      float4 qa = q4[0], qb2 = q4[1], qc2 = q4[2];
      ax[0]  += qa.x * xv[j].x;  ay[0]  += qa.x * xv[j].y;
      ax[1]  += qa.y * xv[j].x;  ay[1]  += qa.y * xv[j].y;
      ax[2]  += qa.z * xv[j].x;  ay[2]  += qa.z * xv[j].y;
      ax[3]  += qa.w * xv[j].x;  ay[3]  += qa.w * xv[j].y;
      ax[4]  += qb2.x * xv[j].x; ay[4]  += qb2.x * xv[j].y;
      ax[5]  += qb2.y * xv[j].x; ay[5]  += qb2.y * xv[j].y;
      ax[6]  += qb2.z * xv[j].x; ay[6]  += qb2.z * xv[j].y;
      ax[7]  += qb2.w * xv[j].x; ay[7]  += qb2.w * xv[j].y;
      ax[8]  += qc2.x * xv[j].x; ay[8]  += qc2.x * xv[j].y;
      ax[9]  += qc2.y * xv[j].x; ay[9]  += qc2.y * xv[j].y;
      ax[10] += qc2.z * xv[j].x; ay[10] += qc2.z * xv[j].y;
      ax[11] += qc2.w * xv[j].x; ay[11] += qc2.w * xv[j].y;
    }
  }
  float* spp = sp + ((size_t)cs * B_ * NH + (size_t)b * NH) * HW_ + m0;
#pragma unroll
  for (int h = 0; h < NH; ++h) {
    float2 v; v.x = ax[h]; v.y = ay[h];
    *(float2*)(spp + (size_t)h * HW_) = v;
  }
}

// ---------------------------------------------------------------------------
// Kernel C: combine partials + qb, softmax over m=4096.
// grid 192, block 1024 (16 waves); each thread owns one float4 of the row.
template <int CS>
__global__ __launch_bounds__(1024) void softmax_kernel(
    const float* __restrict__ sp, const float* __restrict__ qb,
    float* __restrict__ attn) {
  int bh = blockIdx.x;
  int tid = threadIdx.x;  // float4 index within the row
  float qbv = qb[bh];
  const size_t S4 = (size_t)B_ * NH * (HW_ / 4);
  const float4* p = (const float4*)sp + (size_t)bh * (HW_ / 4) + tid;

  float4 v = make_float4(qbv, qbv, qbv, qbv);
#pragma unroll
  for (int s = 0; s < CS; ++s) {
    float4 pv = p[s * S4];
    v.x += pv.x; v.y += pv.y; v.z += pv.z; v.w += pv.w;
  }

  float vmax = fmaxf(fmaxf(v.x, v.y), fmaxf(v.z, v.w));
  for (int off = 32; off; off >>= 1) vmax = fmaxf(vmax, __shfl_xor(vmax, off));
  __shared__ float redm[16], reds[16];
  int w = tid >> 6;
  if ((tid & 63) == 0) redm[w] = vmax;
  __syncthreads();
  vmax = redm[0];
#pragma unroll
  for (int i = 1; i < 16; ++i) vmax = fmaxf(vmax, redm[i]);

  v.x = __expf(v.x - vmax); v.y = __expf(v.y - vmax);
  v.z = __expf(v.z - vmax); v.w = __expf(v.w - vmax);
  float sum = v.x + v.y + v.z + v.w;
  for (int off = 32; off; off >>= 1) sum += __shfl_xor(sum, off);
  if ((tid & 63) == 0) reds[w] = sum;
  __syncthreads();
  float tot = reds[0];
#pragma unroll
  for (int i = 1; i < 16; ++i) tot += reds[i];
  float inv = 1.f / tot;
  v.x *= inv; v.y *= inv; v.z *= inv; v.w *= inv;
  ((float4*)attn)[(size_t)bh * (HW_ / 4) + tid] = v;
}

// ---------------------------------------------------------------------------
// Kernel D: y[b][h][c] = sum_m attn[b,h,m] * x[b,c,m]
// grid (cg=128, b=16), block 256; each block handles 4 consecutive c rows.
__global__ __launch_bounds__(256) void y_kernel(
    const float* __restrict__ x, const float* __restrict__ attn,
    float* __restrict__ y) {
  int cg = blockIdx.x;   // 0..127
  int b  = blockIdx.y;   // 0..15
  int tid = threadIdx.x;
  int c0 = cg * 4;

  float acc[4][NH] = {};
  const float4* xb = (const float4*)(x + (size_t)b * C_ * HW_ + (size_t)c0 * HW_);
  const float4* ab = (const float4*)(attn + (size_t)b * NH * HW_);
#pragma unroll 1
  for (int k = 0; k < 4; ++k) {
    int m4 = k * 256 + tid;
    float4 xv[4];
#pragma unroll
    for (int g = 0; g < 4; ++g) xv[g] = xb[(size_t)g * (HW_ / 4) + m4];
    float4 a[NH];
#pragma unroll
    for (int h = 0; h < NH; ++h) a[h] = ab[(size_t)h * (HW_ / 4) + m4];
#pragma unroll
    for (int g = 0; g < 4; ++g)
#pragma unroll
      for (int h = 0; h < NH; ++h)
        acc[g][h] += a[h].x * xv[g].x + a[h].y * xv[g].y +
                     a[h].z * xv[g].z + a[h].w * xv[g].w;
  }
  // reduce 48 values across the block
#pragma unroll
  for (int g = 0; g < 4; ++g)
#pragma unroll
    for (int h = 0; h < NH; ++h)
      for (int off = 32; off; off >>= 1)
        acc[g][h] += __shfl_xor(acc[g][h], off);

  __shared__ float red[4][48];
  int w = tid >> 6, lane = tid & 63;
  if (lane == 0) {
#pragma unroll
    for (int g = 0; g < 4; ++g)
#pragma unroll
      for (int h = 0; h < NH; ++h) red[w][g * NH + h] = acc[g][h];
  }
  __syncthreads();
  if (tid < 48) {
    float s = red[0][tid] + red[1][tid] + red[2][tid] + red[3][tid];
    int g = tid / NH, h = tid % NH;
    y[((size_t)b * NH + h) * C_ + c0 + g] = s;
  }
}

// ---------------------------------------------------------------------------
// Kernel E: outT[b][t] = bv[t] + sum_c Wv[t,c] * y[b][t/64][c]
__global__ __launch_bounds__(256) void out_kernel(
    const float* __restrict__ Wv, const float* __restrict__ bv,
    const float* __restrict__ y, float* __restrict__ outT) {
  int o = blockIdx.x * 4 + (threadIdx.x >> 6);
  int lane = threadIdx.x & 63;
  int b = o / T_, t = o % T_;
  int h = t / DH;
  const float* wr = Wv + (size_t)t * C_;
  const float* yr = y + ((size_t)b * NH + h) * C_;
  float s = 0.f;
#pragma unroll
  for (int j = 0; j < 8; ++j) { int c = j * 64 + lane; s += wr[c] * yr[c]; }
  for (int off = 32; off; off >>= 1) s += __shfl_xor(s, off);
  if (lane == 0) outT[o] = s + bv[t];
}

// ---------------------------------------------------------------------------
// Kernel F: z[b][c] = bo[c] + sum_t Wo[c,t] * outT[b][t]
__global__ __launch_bounds__(256) void z_kernel(
    const float* __restrict__ Wo, const float* __restrict__ bo,
    const float* __restrict__ outT, float* __restrict__ z) {
  int o = blockIdx.x * 4 + (threadIdx.x >> 6);
  int lane = threadIdx.x & 63;
  int b = o / C_, c = o % C_;
  const float* wr = Wo + (size_t)c * T_;
  const float* orr = outT + (size_t)b * T_;
  float s = 0.f;
#pragma unroll
  for (int j = 0; j < 12; ++j) { int t = j * 64 + lane; s += wr[t] * orr[t]; }
  for (int off = 32; off; off >>= 1) s += __shfl_xor(s, off);
  if (lane == 0) z[o] = s + bo[c];
}

// ---------------------------------------------------------------------------
// Kernel G: out[b,c,i,j] = cond[b,c,i,j] + z[b,c]
// 2 float4/thread; nontemporal (cond never re-read, out never read).
__global__ __launch_bounds__(256) void add_kernel(
    const float* __restrict__ cond, const float* __restrict__ z,
    float* __restrict__ out) {
  size_t i0 = (size_t)blockIdx.x * 512 + threadIdx.x;
  size_t i1 = i0 + 256;
  nfloat4 c0 = __builtin_nontemporal_load(&((const nfloat4*)cond)[i0]);
  nfloat4 c1 = __builtin_nontemporal_load(&((const nfloat4*)cond)[i1]);
  float z0 = z[(int)(i0 >> 10)];  // i0*4/4096
  float z1 = z[(int)(i1 >> 10)];
  nfloat4 r0 = c0 + z0;
  nfloat4 r1 = c1 + z1;
  __builtin_nontemporal_store(r0, &((nfloat4*)out)[i0]);
  __builtin_nontemporal_store(r1, &((nfloat4*)out)[i1]);
}

// ---------------------------------------------------------------------------
template <int CS>
static void run_pipeline(const float* cond, const float* t, const float* Wk,
                         const float* bk, const float* Wv, const float* bv,
                         const float* Wo, const float* bo, float* out,
                         float* ws, int out_size, hipStream_t stream) {
  float* qkT  = ws;
  float* qb   = ws + 98304;
  float* sp   = ws + 98496;
  float* attn = sp + (size_t)CS * 786432;
  float* y    = attn + 786432;
  float* outT = y + 98304;
  float* z    = outT + 12288;

  hipLaunchKernelGGL(qk_kernel, dim3(B_ * NH), dim3(512), 0, stream,
                     t, Wk, bk, qkT, qb);
  hipLaunchKernelGGL((s_kernel<CS>), dim3(8, CS, B_), dim3(256), 0, stream,
                     cond, qkT, sp);
  hipLaunchKernelGGL((softmax_kernel<CS>), dim3(B_ * NH), dim3(1024), 0, stream,
                     sp, qb, attn);
  hipLaunchKernelGGL(y_kernel, dim3(128, B_), dim3(256), 0, stream,
                     cond, attn, y);
  hipLaunchKernelGGL(out_kernel, dim3((B_ * T_) / 4), dim3(256), 0, stream,
                     Wv, bv, y, outT);
  hipLaunchKernelGGL(z_kernel, dim3((B_ * C_) / 4), dim3(256), 0, stream,
                     Wo, bo, outT, z);
  // out_size = 33554432 floats = 8388608 float4 = 16384 blocks * 512
  hipLaunchKernelGGL(add_kernel, dim3(out_size / 4 / 512), dim3(256), 0,
                     stream, cond, z, out);
}

extern "C" void kernel_launch(void* const* d_in, const int* in_sizes, int n_in,
                              void* d_out, int out_size, void* d_ws, size_t ws_size,
                              hipStream_t stream) {
  const float* cond = (const float*)d_in[0];
  const float* t    = (const float*)d_in[1];
  const float* Wk   = (const float*)d_in[2];
  const float* bk   = (const float*)d_in[3];
  const float* Wv   = (const float*)d_in[4];
  const float* bv   = (const float*)d_in[5];
  const float* Wo   = (const float*)d_in[6];
  const float* bo   = (const float*)d_in[7];
  float* out = (float*)d_out;
  float* ws  = (float*)d_ws;

  const size_t need16 = (size_t)(98496 + 16 * 786432 + 786432 + 98304 + 12288 + 8192) * 4;
  const size_t need8  = (size_t)(98496 +  8 * 786432 + 786432 + 98304 + 12288 + 8192) * 4;
  if (ws_size >= need16) {
    run_pipeline<16>(cond, t, Wk, bk, Wv, bv, Wo, bo, out, ws, out_size, stream);
  } else if (ws_size >= need8) {
    run_pipeline<8>(cond, t, Wk, bk, Wv, bv, Wo, bo, out, ws, out_size, stream);
  } else {
    run_pipeline<4>(cond, t, Wk, bk, Wv, bv, Wo, bo, out, ws, out_size, stream);
  }
}

// Round 3
// 320.764 us; speedup vs baseline: 2.0529x; 1.0364x over previous
//
#include <hip/hip_runtime.h>
#include <math.h>

// Problem constants
#define B_   16
#define C_   512
#define HW_  4096
#define T_   768
#define NH   12
#define DH   64

typedef float nfloat4 __attribute__((ext_vector_type(4)));

// Workspace layout (floats), parametrized by CS (c-split count):
//   qkT  @ 0            [B][C][NH]        98304
//   qb   @ 98304        [B*NH]            192
//   sp   @ 98496        [CS][B][NH][HW]   CS*786432
//   attn @ 98496+CS*786432   [B][NH][HW]  786432
//   y    @ attn+786432  [B][NH][C]        98304
//   outT @ y+98304      [B][T]            12288

// ---------------------------------------------------------------------------
// Kernel A: qkT[b][c][h] = (1/8) * sum_dd t[b, h*64+dd] * Wk[h*64+dd, c]
//           qb[b*12+h]   = (1/8) * sum_dd t[b, h*64+dd] * bk[h*64+dd]
__global__ __launch_bounds__(512) void qk_kernel(
    const float* __restrict__ t, const float* __restrict__ Wk,
    const float* __restrict__ bk, float* __restrict__ qkT,
    float* __restrict__ qb) {
  int bh = blockIdx.x;
  int b = bh / NH, h = bh % NH;
  __shared__ float tl[DH];
  int tid = threadIdx.x;
  if (tid < DH) tl[tid] = t[b * T_ + h * DH + tid];
  __syncthreads();
  int c = tid;
  float acc = 0.f;
#pragma unroll
  for (int dd = 0; dd < DH; ++dd)
    acc += tl[dd] * Wk[(h * DH + dd) * C_ + c];
  qkT[((size_t)b * C_ + c) * NH + h] = acc * 0.125f;
  if (tid == 0) {
    float s = 0.f;
    for (int dd = 0; dd < DH; ++dd) s += tl[dd] * bk[h * DH + dd];
    qb[bh] = s * 0.125f;
  }
}

// ---------------------------------------------------------------------------
// Kernel B: partial scores. sp[cs][b][h][m] = sum_{c in cs-range} qk[b,h,c]*x[b,c,m]
// grid (mt=8, cs=CS, b=16), block 128; each thread owns one float4 of m.
// 16 x-loads hoisted per group: 256 B/lane in flight for latency hiding.
template <int CS>
__global__ __launch_bounds__(128) void s_kernel(
    const float* __restrict__ x, const float* __restrict__ qkT,
    float* __restrict__ sp) {
  constexpr int CB = C_ / CS;  // 64 for CS=8
  int mt = blockIdx.x;
  int cs = blockIdx.y;
  int b  = blockIdx.z;
  int tid = threadIdx.x;

  __shared__ float qc[CB * NH];
  const float* src = qkT + ((size_t)b * C_ + cs * CB) * NH;
  for (int i = tid; i < CB * NH; i += 128) qc[i] = src[i];
  __syncthreads();

  int m0 = mt * 512 + tid * 4;
  float4 acc[NH];
#pragma unroll
  for (int h = 0; h < NH; ++h) acc[h] = make_float4(0.f, 0.f, 0.f, 0.f);

  const float* xb = x + (size_t)b * C_ * HW_ + (size_t)(cs * CB) * HW_ + m0;
  for (int c0 = 0; c0 < CB; c0 += 16) {
    float4 xv[16];
#pragma unroll
    for (int j = 0; j < 16; ++j)
      xv[j] = *(const float4*)(xb + (size_t)(c0 + j) * HW_);
#pragma unroll
    for (int j = 0; j < 16; ++j) {
      const float* q = qc + (c0 + j) * NH;
#pragma unroll
      for (int h = 0; h < NH; ++h) {
        float qh = q[h];
        acc[h].x += qh * xv[j].x; acc[h].y += qh * xv[j].y;
        acc[h].z += qh * xv[j].z; acc[h].w += qh * xv[j].w;
      }
    }
  }
  float* spp = sp + ((size_t)cs * B_ * NH + (size_t)b * NH) * HW_ + m0;
#pragma unroll
  for (int h = 0; h < NH; ++h)
    *(float4*)(spp + (size_t)h * HW_) = acc[h];
}

// ---------------------------------------------------------------------------
// Kernel C: combine partials + qb, softmax over m=4096.
// grid 192, block 1024 (16 waves); each thread owns one float4 of the row.
template <int CS>
__global__ __launch_bounds__(1024) void softmax_kernel(
    const float* __restrict__ sp, const float* __restrict__ qb,
    float* __restrict__ attn) {
  int bh = blockIdx.x;
  int tid = threadIdx.x;  // float4 index within the row
  float qbv = qb[bh];
  const size_t S4 = (size_t)B_ * NH * (HW_ / 4);
  const float4* p = (const float4*)sp + (size_t)bh * (HW_ / 4) + tid;

  float4 v = make_float4(qbv, qbv, qbv, qbv);
#pragma unroll
  for (int s = 0; s < CS; ++s) {
    float4 pv = p[s * S4];
    v.x += pv.x; v.y += pv.y; v.z += pv.z; v.w += pv.w;
  }

  float vmax = fmaxf(fmaxf(v.x, v.y), fmaxf(v.z, v.w));
  for (int off = 32; off; off >>= 1) vmax = fmaxf(vmax, __shfl_xor(vmax, off));
  __shared__ float redm[16], reds[16];
  int w = tid >> 6;
  if ((tid & 63) == 0) redm[w] = vmax;
  __syncthreads();
  vmax = redm[0];
#pragma unroll
  for (int i = 1; i < 16; ++i) vmax = fmaxf(vmax, redm[i]);

  v.x = __expf(v.x - vmax); v.y = __expf(v.y - vmax);
  v.z = __expf(v.z - vmax); v.w = __expf(v.w - vmax);
  float sum = v.x + v.y + v.z + v.w;
  for (int off = 32; off; off >>= 1) sum += __shfl_xor(sum, off);
  if ((tid & 63) == 0) reds[w] = sum;
  __syncthreads();
  float tot = reds[0];
#pragma unroll
  for (int i = 1; i < 16; ++i) tot += reds[i];
  float inv = 1.f / tot;
  v.x *= inv; v.y *= inv; v.z *= inv; v.w *= inv;
  ((float4*)attn)[(size_t)bh * (HW_ / 4) + tid] = v;
}

// ---------------------------------------------------------------------------
// Kernel D: y[b][h][c] = sum_m attn[b,h,m] * x[b,c,m]
// grid (cg=128, b=16), block 256; each block handles 4 consecutive c rows.
__global__ __launch_bounds__(256) void y_kernel(
    const float* __restrict__ x, const float* __restrict__ attn,
    float* __restrict__ y) {
  int cg = blockIdx.x;   // 0..127
  int b  = blockIdx.y;   // 0..15
  int tid = threadIdx.x;
  int c0 = cg * 4;

  float acc[4][NH] = {};
  const float4* xb = (const float4*)(x + (size_t)b * C_ * HW_ + (size_t)c0 * HW_);
  const float4* ab = (const float4*)(attn + (size_t)b * NH * HW_);
#pragma unroll 1
  for (int k = 0; k < 4; ++k) {
    int m4 = k * 256 + tid;
    float4 xv[4];
#pragma unroll
    for (int g = 0; g < 4; ++g) xv[g] = xb[(size_t)g * (HW_ / 4) + m4];
    float4 a[NH];
#pragma unroll
    for (int h = 0; h < NH; ++h) a[h] = ab[(size_t)h * (HW_ / 4) + m4];
#pragma unroll
    for (int g = 0; g < 4; ++g)
#pragma unroll
      for (int h = 0; h < NH; ++h)
        acc[g][h] += a[h].x * xv[g].x + a[h].y * xv[g].y +
                     a[h].z * xv[g].z + a[h].w * xv[g].w;
  }
  // reduce 48 values across the block
#pragma unroll
  for (int g = 0; g < 4; ++g)
#pragma unroll
    for (int h = 0; h < NH; ++h)
      for (int off = 32; off; off >>= 1)
        acc[g][h] += __shfl_xor(acc[g][h], off);

  __shared__ float red[4][48];
  int w = tid >> 6, lane = tid & 63;
  if (lane == 0) {
#pragma unroll
    for (int g = 0; g < 4; ++g)
#pragma unroll
      for (int h = 0; h < NH; ++h) red[w][g * NH + h] = acc[g][h];
  }
  __syncthreads();
  if (tid < 48) {
    float s = red[0][tid] + red[1][tid] + red[2][tid] + red[3][tid];
    int g = tid / NH, h = tid % NH;
    y[((size_t)b * NH + h) * C_ + c0 + g] = s;
  }
}

// ---------------------------------------------------------------------------
// Kernel E: outT[b][t] = bv[t] + sum_c Wv[t,c] * y[b][t/64][c]
__global__ __launch_bounds__(256) void out_kernel(
    const float* __restrict__ Wv, const float* __restrict__ bv,
    const float* __restrict__ y, float* __restrict__ outT) {
  int o = blockIdx.x * 4 + (threadIdx.x >> 6);
  int lane = threadIdx.x & 63;
  int b = o / T_, t = o % T_;
  int h = t / DH;
  const float* wr = Wv + (size_t)t * C_;
  const float* yr = y + ((size_t)b * NH + h) * C_;
  float s = 0.f;
#pragma unroll
  for (int j = 0; j < 8; ++j) { int c = j * 64 + lane; s += wr[c] * yr[c]; }
  for (int off = 32; off; off >>= 1) s += __shfl_xor(s, off);
  if (lane == 0) outT[o] = s + bv[t];
}

// ---------------------------------------------------------------------------
// Kernel F (fused z+add): one warp per (b,c) plane.
//   z = bo[c] + sum_t Wo[c,t] * outT[b][t]   (butterfly leaves sum in all lanes)
//   out[b,c,:,:] = cond[b,c,:,:] + z         (16 KB nontemporal stream per warp)
// Removes one dispatch; the GEMV hides under the 268 MB stream.
__global__ __launch_bounds__(256) void zadd_kernel(
    const float* __restrict__ Wo, const float* __restrict__ bo,
    const float* __restrict__ outT, const float* __restrict__ cond,
    float* __restrict__ out) {
  int o = blockIdx.x * 4 + (threadIdx.x >> 6);  // o = b*C + c, 0..8191
  int lane = threadIdx.x & 63;
  int b = o / C_, c = o % C_;
  const float* wr = Wo + (size_t)c * T_;
  const float* orr = outT + (size_t)b * T_;
  float s = 0.f;
#pragma unroll
  for (int j = 0; j < 12; ++j) { int t = j * 64 + lane; s += wr[t] * orr[t]; }
  for (int off = 32; off; off >>= 1) s += __shfl_xor(s, off);
  float zv = s + bo[c];  // full sum present in every lane after butterfly

  const nfloat4* cp = (const nfloat4*)(cond + (size_t)o * HW_);
  nfloat4* op = (nfloat4*)(out + (size_t)o * HW_);
#pragma unroll
  for (int j = 0; j < 16; ++j) {
    nfloat4 cv = __builtin_nontemporal_load(&cp[j * 64 + lane]);
    __builtin_nontemporal_store(cv + zv, &op[j * 64 + lane]);
  }
}

// ---------------------------------------------------------------------------
template <int CS>
static void run_pipeline(const float* cond, const float* t, const float* Wk,
                         const float* bk, const float* Wv, const float* bv,
                         const float* Wo, const float* bo, float* out,
                         float* ws, int out_size, hipStream_t stream) {
  float* qkT  = ws;
  float* qb   = ws + 98304;
  float* sp   = ws + 98496;
  float* attn = sp + (size_t)CS * 786432;
  float* y    = attn + 786432;
  float* outT = y + 98304;

  hipLaunchKernelGGL(qk_kernel, dim3(B_ * NH), dim3(512), 0, stream,
                     t, Wk, bk, qkT, qb);
  hipLaunchKernelGGL((s_kernel<CS>), dim3(8, CS, B_), dim3(128), 0, stream,
                     cond, qkT, sp);
  hipLaunchKernelGGL((softmax_kernel<CS>), dim3(B_ * NH), dim3(1024), 0, stream,
                     sp, qb, attn);
  hipLaunchKernelGGL(y_kernel, dim3(128, B_), dim3(256), 0, stream,
                     cond, attn, y);
  hipLaunchKernelGGL(out_kernel, dim3((B_ * T_) / 4), dim3(256), 0, stream,
                     Wv, bv, y, outT);
  hipLaunchKernelGGL(zadd_kernel, dim3((B_ * C_) / 4), dim3(256), 0, stream,
                     Wo, bo, outT, cond, out);
}

extern "C" void kernel_launch(void* const* d_in, const int* in_sizes, int n_in,
                              void* d_out, int out_size, void* d_ws, size_t ws_size,
                              hipStream_t stream) {
  const float* cond = (const float*)d_in[0];
  const float* t    = (const float*)d_in[1];
  const float* Wk   = (const float*)d_in[2];
  const float* bk   = (const float*)d_in[3];
  const float* Wv   = (const float*)d_in[4];
  const float* bv   = (const float*)d_in[5];
  const float* Wo   = (const float*)d_in[6];
  const float* bo   = (const float*)d_in[7];
  float* out = (float*)d_out;
  float* ws  = (float*)d_ws;

  const size_t need8 = (size_t)(98496 + 8 * 786432 + 786432 + 98304 + 12288) * 4;
  if (ws_size >= need8) {
    run_pipeline<8>(cond, t, Wk, bk, Wv, bv, Wo, bo, out, ws, out_size, stream);
  } else {
    run_pipeline<4>(cond, t, Wk, bk, Wv, bv, Wo, bo, out, ws, out_size, stream);
  }
}